// Round 1
// baseline (348.804 us; speedup 1.0000x reference)
//
#include <hip/hip_runtime.h>
#include <math.h>

// Problem constants (fixed by the reference).
#define BSZ  2
#define DOPN 32
#define RAN  128
#define AZI  128
#define ELE  32
#define NVOX (RAN * AZI * ELE)   // 524288 voxels per batch

__device__ __forceinline__ float sigmoidf_(float t) {
    return 1.0f / (1.0f + __expf(-t));
}

// Kernel A: xyz[b,c,n] = polar->cartesian of coords[b,c,n]. 12.6 MB into d_ws.
__global__ __launch_bounds__(256) void xyz_precompute(
    const float* __restrict__ coords, float* __restrict__ xyz)
{
    const int n = blockIdx.x * 256 + threadIdx.x;
    const int b = blockIdx.y;
    const float* cb = coords + (size_t)b * 3 * NVOX;
    float r = cb[n];
    float a = cb[NVOX + n];
    float e = cb[2 * NVOX + n];
    float sa, ca, se, ce;
    sincosf(a, &sa, &ca);
    sincosf(e, &se, &ce);
    float* xb = xyz + (size_t)b * 3 * NVOX;
    xb[n]            = r * ce * ca;
    xb[NVOX + n]     = r * ce * sa;
    xb[2 * NVOX + n] = r * se;
}

// Kernel B: per-voxel doppler reduction + trilinear warp + loss, block-reduced,
// one scaled atomicAdd per block into out[0].
__global__ __launch_bounds__(256) void seg_dop_loss(
    const float* __restrict__ seg, const float* __restrict__ flow,
    const float* __restrict__ x1, const float* __restrict__ dop_arr,
    const float* __restrict__ ori, const float* __restrict__ gumbels,
    const float* __restrict__ xyz, float* __restrict__ out)
{
    __shared__ float s_dop[DOPN];
    __shared__ float s_wave[4];

    const int b = blockIdx.y;
    if (threadIdx.x < DOPN) s_dop[threadIdx.x] = dop_arr[b * DOPN + threadIdx.x];
    __syncthreads();

    const int n = blockIdx.x * 256 + threadIdx.x;   // grid covers NVOX exactly

    // ---- DOP-axis reductions: argmax(x1+gumbels) and softmax(x1)·dop ----
    const size_t base = (size_t)b * DOPN * NVOX + (size_t)n;
    float xr[DOPN];
    float m_lg = -3.4e38f;
    float m_x  = -3.4e38f;
    int   idx  = 0;
    #pragma unroll
    for (int d = 0; d < DOPN; ++d) {
        float xv = x1[base + (size_t)d * NVOX];
        float gv = gumbels[base + (size_t)d * NVOX];
        xr[d] = xv;
        float lg = xv + gv;          // TAU = 1.0: divide is a no-op
        if (lg > m_lg) { m_lg = lg; idx = d; }   // strict > keeps first (jnp tie rule)
        m_x = fmaxf(m_x, xv);
    }
    float ssum = 0.0f, wsum = 0.0f;
    #pragma unroll
    for (int d = 0; d < DOPN; ++d) {
        float ev = __expf(xr[d] - m_x);
        ssum += ev;
        wsum += ev * s_dop[d];
    }
    const float dop1 = s_dop[idx];
    const float dop2 = wsum / ssum;

    // ---- trilinear warp of xyz volume ----
    const int xI = n & (ELE - 1);
    const int yI = (n >> 5) & (AZI - 1);
    const int zI = n >> 12;

    const float* fl = flow + ((size_t)b * NVOX + (size_t)n) * 3;
    const float fx = fl[0], fy = fl[1], fz = fl[2];

    const float vx = (float)xI + fx;
    const float vy = (float)yI + fy;
    const float vz = (float)zI + fz;

    // replicate reference's normalized-grid round trip, then clamp (border mode)
    const float gx = 2.0f * vx / (float)(ELE - 1) - 1.0f;
    const float gy = 2.0f * vy / (float)(AZI - 1) - 1.0f;
    const float gz = 2.0f * vz / (float)(RAN - 1) - 1.0f;
    const float ix = fminf(fmaxf((gx + 1.0f) * 0.5f * (float)(ELE - 1), 0.0f), (float)(ELE - 1));
    const float iy = fminf(fmaxf((gy + 1.0f) * 0.5f * (float)(AZI - 1), 0.0f), (float)(AZI - 1));
    const float iz = fminf(fmaxf((gz + 1.0f) * 0.5f * (float)(RAN - 1), 0.0f), (float)(RAN - 1));

    const float x0f = floorf(ix), y0f = floorf(iy), z0f = floorf(iz);
    const float wx = ix - x0f, wy = iy - y0f, wz = iz - z0f;
    int x0 = (int)x0f; x0 = x0 < 0 ? 0 : (x0 > ELE - 1 ? ELE - 1 : x0);
    int y0 = (int)y0f; y0 = y0 < 0 ? 0 : (y0 > AZI - 1 ? AZI - 1 : y0);
    int z0 = (int)z0f; z0 = z0 < 0 ? 0 : (z0 > RAN - 1 ? RAN - 1 : z0);
    const int x1c = x0 + 1 > ELE - 1 ? ELE - 1 : x0 + 1;
    const int y1c = y0 + 1 > AZI - 1 ? AZI - 1 : y0 + 1;
    const int z1c = z0 + 1 > RAN - 1 ? RAN - 1 : z0 + 1;

    const float* xb = xyz + (size_t)b * 3 * NVOX;
    const int   zs[2]  = { z0, z1c };
    const int   ys[2]  = { y0, y1c };
    const int   xs[2]  = { x0, x1c };
    const float wzv[2] = { 1.0f - wz, wz };
    const float wyv[2] = { 1.0f - wy, wy };
    const float wxv[2] = { 1.0f - wx, wx };

    float sX = 0.0f, sY = 0.0f, sZ = 0.0f;
    #pragma unroll
    for (int i = 0; i < 2; ++i) {
        #pragma unroll
        for (int j = 0; j < 2; ++j) {
            #pragma unroll
            for (int k = 0; k < 2; ++k) {
                const float w = wzv[i] * wyv[j] * wxv[k];
                const int m = (zs[i] * AZI + ys[j]) * ELE + xs[k];
                sX += w * xb[m];
                sY += w * xb[NVOX + m];
                sZ += w * xb[2 * NVOX + m];
            }
        }
    }

    const float bX = xb[n], bY = xb[NVOX + n], bZ = xb[2 * NVOX + n];
    const float vX = (sX - bX) * 10.0f;   // / INTERVAL (0.1)
    const float vY = (sY - bY) * 10.0f;
    const float vZ = (sZ - bZ) * 10.0f;

    const float* ob = ori + (size_t)b * 3 * NVOX;
    const float dop_label = vX * ob[n] + vY * ob[NVOX + n] + vZ * ob[2 * NVOX + n];

    float e1 = dop_label - dop1; e1 *= e1;
    float e2 = dop_label - dop2; e2 *= e2;
    const float seg_label = 0.5f * (sigmoidf_(10.0f * (0.15f - e1)) +
                                    sigmoidf_(10.0f * (0.15f - e2)));
    const float seg_sig = sigmoidf_(seg[(size_t)b * NVOX + n]);
    float contrib = fabsf(seg_sig - seg_label);

    // ---- block reduction: wave64 shuffle, then 4 partials in LDS ----
    #pragma unroll
    for (int off = 32; off > 0; off >>= 1)
        contrib += __shfl_down(contrib, off, 64);
    const int lane = threadIdx.x & 63;
    const int wid  = threadIdx.x >> 6;
    if (lane == 0) s_wave[wid] = contrib;
    __syncthreads();
    if (threadIdx.x == 0) {
        const float bsum = s_wave[0] + s_wave[1] + s_wave[2] + s_wave[3];
        atomicAdd(out, bsum * (1.0f / ((float)BSZ * (float)NVOX)));
    }
}

extern "C" void kernel_launch(void* const* d_in, const int* in_sizes, int n_in,
                              void* d_out, int out_size, void* d_ws, size_t ws_size,
                              hipStream_t stream) {
    const float* seg    = (const float*)d_in[0];
    const float* flow   = (const float*)d_in[1];
    const float* x1     = (const float*)d_in[2];
    const float* dopar  = (const float*)d_in[3];
    const float* coords = (const float*)d_in[4];
    const float* ori    = (const float*)d_in[5];
    const float* gumb   = (const float*)d_in[6];
    float* out = (float*)d_out;
    float* xyz = (float*)d_ws;   // needs 3*BSZ*NVOX*4 = 12.6 MB

    hipMemsetAsync(d_out, 0, sizeof(float) * (size_t)out_size, stream);

    dim3 grid(NVOX / 256, BSZ);
    xyz_precompute<<<grid, 256, 0, stream>>>(coords, xyz);
    seg_dop_loss<<<grid, 256, 0, stream>>>(seg, flow, x1, dopar, ori, gumb, xyz, out);
}